// Round 7
// baseline (648.407 us; speedup 1.0000x reference)
//
#include <hip/hip_runtime.h>
#include <hip/hip_bf16.h>
#include <math.h>

// ---------------------------------------------------------------------------
// TAPIR forward. State f32; cv + mixer GEMMs + hid2/hid3 convs via bf16 MFMA.
// fg[64,64,256] hg[128,128,128] qf[1024,256] hq[1024,128] -> out[1024,4]
// 3 dispatches: prep+cv, head stripes, fused refine (merge + 4x(corr,mix1,mix2))
// ---------------------------------------------------------------------------

#define NQ 1024
#define TEMPF 20.0f
#define DIMV 388
#define INDIM 535
#define KPAD 544
#define HID 512

// workspace layout (float offsets)
#define WS_CVB     0
#define WS_WIT     2097152                    // bf16 [512][544]
#define WS_WOT     2236416                    // bf16 [448][512]
#define WS_FG16    2351104                    // bf16 fg copy (1048576)
#define WS_HG16    2875392                    // bf16 hg copy (2097152)
#define WS_AV16    3923968                    // bf16 fgavg copy (262144)
#define WS_FGAVG   4194304                    // (unused; kept for layout)
#define WS_POS     (WS_FGAVG + 262144)
#define WS_OCC     (WS_POS + NQ*2)
#define WS_EXPD    (WS_OCC + NQ)
#define WS_FEATS   (WS_EXPD + NQ)             // f32 [1024][384]
#define WS_MLPIN   (WS_FEATS + NQ*384)        // bf16 mlp_in [1024][544]
#define WS_HIDDEN  (WS_MLPIN + NQ*KPAD)       // SUM3 overlay region
#define WS_W3B     (WS_HIDDEN + NQ*HID)       // bf16 hid3 B-fragments (5120)
#define WS_W2B     (WS_W3B + 2560)            // bf16 hid2 B-fragments (2560)
#define WS_PART    (WS_MLPIN + 278528)        // softmax partials overlay
#define WS_SUM3    WS_HIDDEN                  // hid3 relu-sums overlay

#define CVP 68                                // cvs LDS pitch
#define ROWP 2368                             // occ_t row pitch bytes
#define MIP 552                               // mi_s row pitch (bf16), 2-way banks
#define HP  520                               // hidden_s row pitch (bf16)

typedef __attribute__((ext_vector_type(8))) short bf16x8;
typedef __attribute__((ext_vector_type(4))) float f32x4;

union BU8 { uint4 u; __hip_bfloat16 h[8]; };

__device__ __forceinline__ int occ_off(int r, int idx, int c) {
  int o = idx * 32 + c * 2;
  o ^= ((idx >> 2) & 3) << 4;
  return r * ROWP + o;
}

// ---------------------------------------------------------------------------
// fused prep + cost volume + all bf16 conversions. (unchanged from round 6)
// ---------------------------------------------------------------------------
__global__ __launch_bounds__(256) void k_prep_cv(
    const float* __restrict__ fg, const float* __restrict__ hg,
    const float* __restrict__ qf, const float* __restrict__ hq,
    const float* __restrict__ w3, const float* __restrict__ w2,
    const float* __restrict__ wi, const float* __restrict__ wo,
    float* __restrict__ ws) {
  __shared__ __hip_bfloat16 A_s[32 * 32];
  __shared__ __hip_bfloat16 B_s[64 * 32];
  const int bx = blockIdx.x;
  const int t = threadIdx.x;

  if (bx >= 2048) {
    int i = (bx - 2048) * 256 + t;
    if (i < 262144) {
      int c = i & 255, ox = (i >> 8) & 31, oy = i >> 13;
      const float* b = fg + (((oy * 2) * 64 + ox * 2) << 8) + c;
      float av = 0.25f * (b[0] + b[256] + b[16384] + b[16384 + 256]);
      ((__hip_bfloat16*)(ws + WS_AV16))[i] = __float2bfloat16(av);
    } else if (i < 655360) {
      int j = i - 262144;
      int n = j / 384, c = j - n * 384;
      float v = (c < 128) ? hq[n * 128 + c] : qf[n * 256 + c - 128];
      ws[WS_FEATS + j] = v;
      __hip_bfloat16* mi = (__hip_bfloat16*)(ws + WS_MLPIN);
      mi[n * KPAD + 4 + c] = __float2bfloat16(v);
      if (c == 0) {
        mi[n * KPAD + 0] = __float2bfloat16(0.f);
        mi[n * KPAD + 1] = __float2bfloat16(0.f);
      }
    } else if (i < 660480) {
      int j = i - 655360;
      int e = j & 7, qd = (j >> 3) & 3, nl = (j >> 5) & 15;
      int nt = (j >> 9) & 1, kt = j >> 10;
      int k = kt * 32 + qd * 8 + e;
      int ic = k & 15, tap = k >> 4;
      int oc = nt * 16 + nl;
      float v = (tap < 9) ? w3[(oc * 16 + ic) * 9 + tap] : 0.f;
      ((__hip_bfloat16*)(ws + WS_W3B))[j] = __float2bfloat16(v);
    } else if (i < 663040) {
      int j = i - 660480;
      int e = j & 7, qd = (j >> 3) & 3, kt = j >> 9;
      int k = kt * 32 + qd * 8 + e;
      int ch = k & 15, tap = k >> 4;
      float v = (tap < 9) ? w2[ch * 9 + tap] : 0.f;
      ((__hip_bfloat16*)(ws + WS_W2B))[j] = __float2bfloat16(v);
    } else if (i < 1187328) {
      ws[WS_SUM3 + (i - 663040)] = 0.f;
    } else if (i < 1465856) {
      int j = i - 1187328;
      int n = j / KPAD, k = j - n * KPAD;
      float v = (k < INDIM) ? wi[k * HID + n] : 0.f;
      ((__hip_bfloat16*)(ws + WS_WIT))[j] = __float2bfloat16(v);
    } else if (i < 1695232) {
      int j = i - 1465856;
      int n = j >> 9, k = j & 511;
      float v = (n < DIMV) ? wo[k * DIMV + n] : 0.f;
      ((__hip_bfloat16*)(ws + WS_WOT))[j] = __float2bfloat16(v);
    } else if (i < 1957376) {
      int j = (i - 1695232) * 4;
      float4 v = *(const float4*)&fg[j];
      union { __hip_bfloat16 h[4]; uint2 u; } pk;
      pk.h[0] = __float2bfloat16(v.x); pk.h[1] = __float2bfloat16(v.y);
      pk.h[2] = __float2bfloat16(v.z); pk.h[3] = __float2bfloat16(v.w);
      *(uint2*)(((__hip_bfloat16*)(ws + WS_FG16)) + j) = pk.u;
    } else {
      int j = (i - 1957376) * 4;
      float4 v = *(const float4*)&hg[j];
      union { __hip_bfloat16 h[4]; uint2 u; } pk;
      pk.h[0] = __float2bfloat16(v.x); pk.h[1] = __float2bfloat16(v.y);
      pk.h[2] = __float2bfloat16(v.z); pk.h[3] = __float2bfloat16(v.w);
      *(uint2*)(((__hip_bfloat16*)(ws + WS_HG16)) + j) = pk.u;
    }
    return;
  }

  // ---- cv part ----
  const int wv = t >> 6, lane = t & 63;
  const int wm = wv & 1, wn = wv >> 1;
  const int quad = lane >> 4, nl = lane & 15;
  const int p0 = (bx & 63) * 64, m0 = (bx >> 6) * 32;
  f32x4 acc0 = {0.f, 0.f, 0.f, 0.f};
  f32x4 acc1 = {0.f, 0.f, 0.f, 0.f};

  for (int k0 = 0; k0 < 256; k0 += 32) {
    {
      int r = t >> 3, c = t & 7;
      float4 v = *(const float4*)&qf[(m0 + r) * 256 + k0 + c * 4];
      union { __hip_bfloat16 h[4]; uint2 u; } pk;
      pk.h[0] = __float2bfloat16(v.x); pk.h[1] = __float2bfloat16(v.y);
      pk.h[2] = __float2bfloat16(v.z); pk.h[3] = __float2bfloat16(v.w);
      *(uint2*)&A_s[r * 32 + c * 4] = pk.u;
    }
    {
      int r = t >> 2, c = t & 3;
      const float* src = &fg[(p0 + r) * 256 + k0 + c * 8];
      float4 v0 = *(const float4*)src;
      float4 v1 = *(const float4*)(src + 4);
      union { __hip_bfloat16 h[8]; uint4 u; } pk;
      pk.h[0] = __float2bfloat16(v0.x); pk.h[1] = __float2bfloat16(v0.y);
      pk.h[2] = __float2bfloat16(v0.z); pk.h[3] = __float2bfloat16(v0.w);
      pk.h[4] = __float2bfloat16(v1.x); pk.h[5] = __float2bfloat16(v1.y);
      pk.h[6] = __float2bfloat16(v1.z); pk.h[7] = __float2bfloat16(v1.w);
      *(uint4*)&B_s[r * 32 + c * 8] = pk.u;
    }
    __syncthreads();
    bf16x8 a = *(const bf16x8*)&A_s[(16 * wm + nl) * 32 + quad * 8];
    bf16x8 b0 = *(const bf16x8*)&B_s[(32 * wn + nl) * 32 + quad * 8];
    bf16x8 b1 = *(const bf16x8*)&B_s[(32 * wn + 16 + nl) * 32 + quad * 8];
    acc0 = __builtin_amdgcn_mfma_f32_16x16x32_bf16(a, b0, acc0, 0, 0, 0);
    acc1 = __builtin_amdgcn_mfma_f32_16x16x32_bf16(a, b1, acc1, 0, 0, 0);
    __syncthreads();
  }
  __hip_bfloat16* cvb = (__hip_bfloat16*)ws;
#pragma unroll
  for (int nt = 0; nt < 2; nt++) {
    int n = p0 + 32 * wn + nt * 16 + nl;
#pragma unroll
    for (int r = 0; r < 4; r++) {
      int m = m0 + 16 * wm + quad * 4 + r;
      cvb[m * 4096 + n] = __float2bfloat16(nt ? acc1[r] : acc0[r]);
    }
  }
}

// ---------------------------------------------------------------------------
// head stripe kernel (unchanged from round 6): 16384 blocks.
// ---------------------------------------------------------------------------
__global__ __launch_bounds__(256, 5) void k_head_stripe(
    const float* __restrict__ h1w, const float* __restrict__ h1b,
    const float* __restrict__ h2b, const float* __restrict__ h3b,
    float* __restrict__ ws) {
  __shared__ float cvs[8 * CVP];
  __shared__ float4 occ_t4[6 * ROWP / 16];
  char* occ_t = (char*)occ_t4;

  const int bx = blockIdx.x;
  const int q = bx >> 4, st = bx & 15;
  const int y0 = st * 4;
  const int t = threadIdx.x;
  const int wv = t >> 6, lane = t & 63;
  const int role = (wv + bx) & 3;
  const __hip_bfloat16* cvb = (const __hip_bfloat16*)ws + q * 4096;

  if (t < 192) {
    int r = t >> 5, j = t & 31;
    int off = r * ROWP + ((j < 16) ? j * 8 : 2176 + (j - 16) * 8);
    *(uint2*)(occ_t + off) = make_uint2(0u, 0u);
  }
  if (st == 0 || st == 15) {
    int r = (st == 0) ? 0 : 5;
    for (int i = t; i < 288; i += 256)
      *(uint2*)(occ_t + r * ROWP + i * 8) = make_uint2(0u, 0u);
  }
#pragma unroll
  for (int j = 0; j < 2; j++) {
    int i = t + 256 * j;
    int lr = i >> 6, x = i & 63;
    int g = y0 - 2 + lr;
    cvs[lr * CVP + x + 1] =
        (g >= 0 && g < 64) ? __bfloat162float(cvb[g * 64 + x]) : 0.f;
  }
  if (t < 32) {
    int rr = t >> 2, c = t & 3;
    cvs[rr * CVP + ((c == 0) ? 0 : (64 + c))] = 0.f;
  }
  __syncthreads();

  {
    const int x = lane;
    const int chg = wv * 4;
    float w1r[4][9], b1r[4];
#pragma unroll
    for (int k = 0; k < 4; k++) {
      b1r[k] = h1b[chg + k];
#pragma unroll
      for (int j = 0; j < 9; j++) w1r[k][j] = h1w[(chg + k) * 9 + j];
    }
    float win[3][3];
#pragma unroll
    for (int j = 0; j < 3; j++) {
      const float* cp = &cvs[j * CVP + x];
      win[j][0] = cp[0]; win[j][1] = cp[1]; win[j][2] = cp[2];
    }
    for (int r = 0; r < 6; r++) {
      if (r > 0) {
#pragma unroll
        for (int c = 0; c < 3; c++) { win[0][c] = win[1][c]; win[1][c] = win[2][c]; }
        const float* cp = &cvs[(r + 2) * CVP + x];
        win[2][0] = cp[0]; win[2][1] = cp[1]; win[2][2] = cp[2];
      }
      int yo = y0 - 1 + r;
      if (yo >= 0 && yo <= 63) {
        union { __hip_bfloat16 h[4]; uint2 u; } pk;
#pragma unroll
        for (int k = 0; k < 4; k++) {
          float a = b1r[k];
#pragma unroll
          for (int ky = 0; ky < 3; ky++)
            a += w1r[k][3 * ky] * win[ky][0] + w1r[k][3 * ky + 1] * win[ky][1] +
                 w1r[k][3 * ky + 2] * win[ky][2];
          pk.h[k] = __float2bfloat16(fmaxf(a, 0.f));
        }
        *(uint2*)(occ_t + occ_off(r, x + 4, chg)) = pk.u;
      }
    }
  }
  __syncthreads();

  const int nl = lane & 15;
  const int qd = lane >> 4, qh = qd >> 1, ql = qd & 1;

  if (role == 1 || role == 2) {
    const __hip_bfloat16* W3B = (const __hip_bfloat16*)(ws + WS_W3B);
    const int oyl = role - 1;
    f32x4 acc00 = {0.f,0.f,0.f,0.f}, acc01 = {0.f,0.f,0.f,0.f};
    f32x4 acc10 = {0.f,0.f,0.f,0.f}, acc11 = {0.f,0.f,0.f,0.f};
#pragma unroll
    for (int kt = 0; kt < 5; kt++) {
      int tap = kt * 2 + qh;
      bf16x8 a0, a1;
      if (tap < 9) {
        int ky = (tap >= 6) ? 2 : ((tap >= 3) ? 1 : 0);
        int kx = tap - 3 * ky;
        int R = 2 * oyl + 1 + ky;
        int idx0 = 4 + kx + 2 * nl;
        a0 = *(const bf16x8*)(occ_t + occ_off(R, idx0, ql * 8));
        a1 = *(const bf16x8*)(occ_t + occ_off(R, idx0 + 32, ql * 8));
      } else {
        a0 = (bf16x8){0, 0, 0, 0, 0, 0, 0, 0};
        a1 = a0;
      }
      bf16x8 b0 = *(const bf16x8*)&W3B[((kt * 2 + 0) * 16 + nl) * 32 + qd * 8];
      bf16x8 b1 = *(const bf16x8*)&W3B[((kt * 2 + 1) * 16 + nl) * 32 + qd * 8];
      acc00 = __builtin_amdgcn_mfma_f32_16x16x32_bf16(a0, b0, acc00, 0, 0, 0);
      acc01 = __builtin_amdgcn_mfma_f32_16x16x32_bf16(a0, b1, acc01, 0, 0, 0);
      acc10 = __builtin_amdgcn_mfma_f32_16x16x32_bf16(a1, b0, acc10, 0, 0, 0);
      acc11 = __builtin_amdgcn_mfma_f32_16x16x32_bf16(a1, b1, acc11, 0, 0, 0);
    }
    float bb0 = h3b[nl], bb1 = h3b[16 + nl];
    float s0 = 0.f, s1 = 0.f;
#pragma unroll
    for (int r = 0; r < 4; r++) {
      s0 += fmaxf(acc00[r] + bb0, 0.f) + fmaxf(acc10[r] + bb0, 0.f);
      s1 += fmaxf(acc01[r] + bb1, 0.f) + fmaxf(acc11[r] + bb1, 0.f);
    }
    s0 += __shfl_xor(s0, 16); s0 += __shfl_xor(s0, 32);
    s1 += __shfl_xor(s1, 16); s1 += __shfl_xor(s1, 32);
    if (lane < 16) {
      atomicAdd(&ws[WS_SUM3 + (q * 16 + st) * 32 + nl], s0);
      atomicAdd(&ws[WS_SUM3 + (q * 16 + st) * 32 + 16 + nl], s1);
    }
  } else {
    const int rl0 = (role == 3) ? 2 : 0;
    const __hip_bfloat16* W2B = (const __hip_bfloat16*)(ws + WS_W2B);
    bf16x8 wb0 = *(const bf16x8*)&W2B[(0 * 16 + nl) * 32 + qd * 8];
    bf16x8 wb1 = *(const bf16x8*)&W2B[(1 * 16 + nl) * 32 + qd * 8];
    bf16x8 wb2 = *(const bf16x8*)&W2B[(2 * 16 + nl) * 32 + qd * 8];
    bf16x8 wb3 = *(const bf16x8*)&W2B[(3 * 16 + nl) * 32 + qd * 8];
    bf16x8 wb4 = *(const bf16x8*)&W2B[(4 * 16 + nl) * 32 + qd * 8];
    f32x4 pa0 = {0.f,0.f,0.f,0.f}, pa1 = {0.f,0.f,0.f,0.f};
    f32x4 pa2 = {0.f,0.f,0.f,0.f}, pa3 = {0.f,0.f,0.f,0.f};
    f32x4 pa4 = {0.f,0.f,0.f,0.f}, pa5 = {0.f,0.f,0.f,0.f};
    f32x4 pa6 = {0.f,0.f,0.f,0.f}, pa7 = {0.f,0.f,0.f,0.f};

#define H2STEP(ACC, ROW, XT, KT, WB)                                         \
    {                                                                        \
      int tap = (KT) * 2 + qh;                                               \
      bf16x8 a;                                                              \
      if (tap < 9) {                                                         \
        int ky = (tap >= 6) ? 2 : ((tap >= 3) ? 1 : 0);                      \
        int kx = tap - 3 * ky;                                               \
        a = *(const bf16x8*)(occ_t +                                         \
            occ_off((ROW) + ky, (XT) + nl + 3 + kx, ql * 8));                \
      } else { a = (bf16x8){0, 0, 0, 0, 0, 0, 0, 0}; }                       \
      ACC = __builtin_amdgcn_mfma_f32_16x16x32_bf16(a, WB, ACC, 0, 0, 0);    \
    }
#define H2TILE(ACC, ROW, XT)                                                 \
    H2STEP(ACC, ROW, XT, 0, wb0) H2STEP(ACC, ROW, XT, 1, wb1)                \
    H2STEP(ACC, ROW, XT, 2, wb2) H2STEP(ACC, ROW, XT, 3, wb3)                \
    H2STEP(ACC, ROW, XT, 4, wb4)

    H2TILE(pa0, rl0, 0)      H2TILE(pa1, rl0, 16)
    H2TILE(pa2, rl0, 32)     H2TILE(pa3, rl0, 48)
    H2TILE(pa4, rl0 + 1, 0)  H2TILE(pa5, rl0 + 1, 16)
    H2TILE(pa6, rl0 + 1, 32) H2TILE(pa7, rl0 + 1, 48)
#undef H2TILE
#undef H2STEP

    const float bb = h2b[0];
    float mg = -1e30f;
#pragma unroll
    for (int r = 0; r < 4; r++) {
      mg = fmaxf(mg, fmaxf(fmaxf(pa0[r], pa1[r]), fmaxf(pa2[r], pa3[r])));
      mg = fmaxf(mg, fmaxf(fmaxf(pa4[r], pa5[r]), fmaxf(pa6[r], pa7[r])));
    }
    mg = (mg + bb) * TEMPF;
    mg = fmaxf(mg, __shfl_xor(mg, 16));
    mg = fmaxf(mg, __shfl_xor(mg, 32));
    float sa = 0.f, sb = 0.f, sx = 0.f;
    const float fq = (float)(qd * 4);
#pragma unroll
    for (int r = 0; r < 4; r++) {
      float xr = fq + (float)r;
      float e;
      e = __expf((pa0[r] + bb) * TEMPF - mg); sa += e; sx += e * (xr + 0.f);
      e = __expf((pa1[r] + bb) * TEMPF - mg); sa += e; sx += e * (xr + 16.f);
      e = __expf((pa2[r] + bb) * TEMPF - mg); sa += e; sx += e * (xr + 32.f);
      e = __expf((pa3[r] + bb) * TEMPF - mg); sa += e; sx += e * (xr + 48.f);
      e = __expf((pa4[r] + bb) * TEMPF - mg); sb += e; sx += e * (xr + 0.f);
      e = __expf((pa5[r] + bb) * TEMPF - mg); sb += e; sx += e * (xr + 16.f);
      e = __expf((pa6[r] + bb) * TEMPF - mg); sb += e; sx += e * (xr + 32.f);
      e = __expf((pa7[r] + bb) * TEMPF - mg); sb += e; sx += e * (xr + 48.f);
    }
    float ya = (float)(y0 + rl0);
    float s = sa + sb;
    float sy = ya * sa + (ya + 1.f) * sb;
    s += __shfl_xor(s, 16); sx += __shfl_xor(sx, 16); sy += __shfl_xor(sy, 16);
    s += __shfl_xor(s, 32); sx += __shfl_xor(sx, 32); sy += __shfl_xor(sy, 32);
    if (lane == 0) {
      int slot = q * 32 + st * 2 + ((role == 3) ? 1 : 0);
      *(float4*)&ws[WS_PART + slot * 4] = make_float4(mg, s, sx, sy);
    }
  }
}

// ---------------------------------------------------------------------------
__device__ __forceinline__ float gelu_tanh(float x) {
  float z = 0.7978845608028654f * (x + 0.044715f * x * x * x);
  z = fminf(fmaxf(z, -15.f), 15.f);
  float e = __expf(2.f * z);
  float th = (e - 1.f) / (e + 1.f);
  return 0.5f * x * (1.f + th);
}

// ---------------------------------------------------------------------------
// fused refine: 1 block = 8 queries, 256 threads. merge-init + 4 iterations
// of (corr -> mix1 -> mix2) entirely in LDS. MFMA tiles are M=16 with rows
// 0..7 valid (GEMM rows are independent; pad rows zeroed once).
// ---------------------------------------------------------------------------
__global__ __launch_bounds__(256) void k_refine(
    const float* __restrict__ w4, const float* __restrict__ b4,
    const float* __restrict__ w5, const float* __restrict__ b5,
    const float* __restrict__ bi, const float* __restrict__ bo,
    float* __restrict__ ws, float* __restrict__ out) {
  __shared__ __align__(16) __hip_bfloat16 mi_s[16 * MIP];   // 17664 B
  __shared__ __align__(16) char hv[16 * HP * 2];            // 16640 B (hidden/dbuf)
  __shared__ __align__(16) float feats_s[8][384];           // 12288 B
  __shared__ float pos_s[8][2];
  __shared__ float occ_s[8], expd_s[8];
  __shared__ float sums_r[4][32];
  __shared__ float o4_r[4][16];
  __hip_bfloat16* hidden_s = (__hip_bfloat16*)hv;
  float* dbuf = (float*)hv;                                 // 8*192 floats

  const int t = threadIdx.x;
  const int wv = t >> 6, lane = t & 63;
  const int q0 = blockIdx.x * 8;
  const int nl = lane & 15, quad = lane >> 4;

  // ---- init loads ----
  {
    const __hip_bfloat16* mig = (const __hip_bfloat16*)(ws + WS_MLPIN);
    for (int j = t; j < 544; j += 256) {          // 8 rows x 68 uint4
      int r = j / 68, c = j - r * 68;
      *(uint4*)&mi_s[r * MIP + c * 8] =
          *(const uint4*)&mig[(q0 + r) * KPAD + c * 8];
    }
    uint* z = (uint*)&mi_s[8 * MIP];              // zero pad rows 8..15
    for (int j = t; j < 2208; j += 256) z[j] = 0u;
    for (int j = t; j < 768; j += 256) {          // feats 8 x 96 float4
      int r = j / 96, c = j - r * 96;
      *(float4*)&feats_s[r][c * 4] =
          *(const float4*)&ws[WS_FEATS + (q0 + r) * 384 + c * 4];
    }
  }
  // ---- merge-init: each wave reduces 2 queries ----
  for (int rep = 0; rep < 2; ++rep) {
    int qi = wv * 2 + rep;
    int q = q0 + qi;
    float M = -1e30f, S = 0.f, SX = 0.f, SY = 0.f;
    if (lane < 32) {
      float4 pv = *(const float4*)&ws[WS_PART + (q * 32 + lane) * 4];
      M = pv.x; S = pv.y; SX = pv.z; SY = pv.w;
    }
#pragma unroll
    for (int off = 1; off < 64; off <<= 1) {
      float Mo = __shfl_xor(M, off), So = __shfl_xor(S, off);
      float SXo = __shfl_xor(SX, off), SYo = __shfl_xor(SY, off);
      float Mn = fmaxf(M, Mo);
      float c1 = __expf(M - Mn), c2 = __expf(Mo - Mn);
      S = S * c1 + So * c2; SX = SX * c1 + SXo * c2; SY = SY * c1 + SYo * c2;
      M = Mn;
    }
    if (lane == 0) {
      pos_s[qi][0] = (SX / S) * 8.0f;
      pos_s[qi][1] = (SY / S) * 8.0f;
    }
    int ch = lane & 31, half = lane >> 5;
    float sm = 0.f;
#pragma unroll
    for (int s8 = 0; s8 < 8; s8++)
      sm += ws[WS_SUM3 + (q * 16 + half * 8 + s8) * 32 + ch];
    sm += __shfl_xor(sm, 32);
    if (lane < 32) sums_r[wv][lane] = sm * (1.f / 1024.f);
    __syncthreads();
    if (lane < 16) {
      float a = b4[lane];
#pragma unroll
      for (int i = 0; i < 32; i++) a += sums_r[wv][i] * w4[i * 16 + lane];
      o4_r[wv][lane] = fmaxf(a, 0.f);
    }
    __syncthreads();
    if (lane < 2) {
      float r = b5[lane];
#pragma unroll
      for (int j = 0; j < 16; j++) r += o4_r[wv][j] * w5[j * 2 + lane];
      if (lane == 0) { occ_s[qi] = r;  mi_s[qi * MIP + 2] = __float2bfloat16(r); }
      else           { expd_s[qi] = r; mi_s[qi * MIP + 3] = __float2bfloat16(r); }
    }
    __syncthreads();
  }

  const __hip_bfloat16* G0 = (const __hip_bfloat16*)(ws + WS_HG16);
  const __hip_bfloat16* G1 = (const __hip_bfloat16*)(ws + WS_FG16);
  const __hip_bfloat16* G2 = (const __hip_bfloat16*)(ws + WS_AV16);
  const unsigned short* WIT = (const unsigned short*)(ws + WS_WIT);
  const unsigned short* WOT = (const unsigned short*)(ws + WS_WOT);
  const int cq = t >> 5, sl = t & 31;            // 32 threads per query
  const int cl = sl & 15, ph = sl >> 4;          // 16-ch split x 2-point split

  for (int it = 0; it < 4; ++it) {
    // ---- corr: dots into dbuf ----
    {
      float posx = pos_s[cq][0], posy = pos_s[cq][1];
      float qh[8], qq[16];
#pragma unroll
      for (int j = 0; j < 8; j++) qh[j] = feats_s[cq][cl * 8 + j];
#pragma unroll
      for (int j = 0; j < 16; j++) qq[j] = feats_s[cq][128 + cl * 16 + j];
      float* db = dbuf + cq * 192;
#pragma unroll
      for (int L = 0; L < 3; L++) {
        const __hip_bfloat16* grid;
        int Hg, Wg;
        float scl;
        if (L == 0)      { grid = G0; Hg = 128; Wg = 128; scl = 0.25f; }
        else if (L == 1) { grid = G1; Hg = 64;  Wg = 64;  scl = 0.125f; }
        else             { grid = G2; Hg = 32;  Wg = 32;  scl = 0.0625f; }
        float cy = posy * scl, cx = posx * scl;
        int iy = (int)floorf(cy), ix = (int)floorf(cx);
        for (int p2 = 0; p2 < 32; ++p2) {
          int p = p2 * 2 + ph;
          int a = p >> 3, b = p & 7;
          int row = iy + a - 3; row = row < 0 ? 0 : (row > Hg - 1 ? Hg - 1 : row);
          int col = ix + b - 3; col = col < 0 ? 0 : (col > Wg - 1 ? Wg - 1 : col);
          float acc = 0.f;
          if (L == 0) {
            BU8 g0; g0.u = *(const uint4*)(grid + (row * Wg + col) * 128 + cl * 8);
#pragma unroll
            for (int j = 0; j < 8; j++) acc += __bfloat162float(g0.h[j]) * qh[j];
          } else {
            const __hip_bfloat16* gp = grid + (row * Wg + col) * 256 + cl * 16;
            BU8 g0, g1;
            g0.u = *(const uint4*)gp;
            g1.u = *(const uint4*)(gp + 8);
#pragma unroll
            for (int j = 0; j < 8; j++) {
              acc += __bfloat162float(g0.h[j]) * qq[j];
              acc += __bfloat162float(g1.h[j]) * qq[8 + j];
            }
          }
          acc += __shfl_xor(acc, 1);
          acc += __shfl_xor(acc, 2);
          acc += __shfl_xor(acc, 4);
          acc += __shfl_xor(acc, 8);
          if (cl == 0) db[L * 64 + p] = acc;
        }
      }
    }
    __syncthreads();
    // ---- bilinear -> mi corr columns ----
    for (int j = t; j < 8 * 147; j += 256) {
      int qi = j / 147, s = j - qi * 147;
      int L = s / 49, ss = s - L * 49;
      int sa = ss / 7, sb = ss - sa * 7;
      float scl = (L == 0) ? 0.25f : ((L == 1) ? 0.125f : 0.0625f);
      float cy = pos_s[qi][1] * scl, cx = pos_s[qi][0] * scl;
      float wy = cy - floorf(cy), wx = cx - floorf(cx);
      const float* db = dbuf + qi * 192 + L * 64;
      int i00 = sa * 8 + sb;
      float d00 = db[i00], d01 = db[i00 + 1];
      float d10 = db[i00 + 8], d11 = db[i00 + 9];
      float corr = (1.f - wy) * (1.f - wx) * d00 + (1.f - wy) * wx * d01 +
                   wy * (1.f - wx) * d10 + wy * wx * d11;
      mi_s[qi * MIP + 388 + s] = __float2bfloat16(corr);
    }
    __syncthreads();
    // ---- mix1: 32 n-tiles, 8/wave in pairs; A-frags in registers ----
    {
      bf16x8 af[17];
#pragma unroll
      for (int j = 0; j < 17; j++)
        af[j] = *(const bf16x8*)&mi_s[nl * MIP + j * 32 + quad * 8];
#pragma unroll
      for (int tp = 0; tp < 4; ++tp) {
        int n0a = (wv * 8 + tp * 2) * 16;
        int n0b = n0a + 16;
        const unsigned short* bpa = &WIT[(n0a + nl) * KPAD + quad * 8];
        const unsigned short* bpb = &WIT[(n0b + nl) * KPAD + quad * 8];
        f32x4 aca = {0.f, 0.f, 0.f, 0.f}, acb = {0.f, 0.f, 0.f, 0.f};
#pragma unroll
        for (int ks = 0; ks < 17; ks++) {
          bf16x8 ba = *(const bf16x8*)(bpa + ks * 32);
          bf16x8 bb = *(const bf16x8*)(bpb + ks * 32);
          aca = __builtin_amdgcn_mfma_f32_16x16x32_bf16(af[ks], ba, aca, 0, 0, 0);
          acb = __builtin_amdgcn_mfma_f32_16x16x32_bf16(af[ks], bb, acb, 0, 0, 0);
        }
        float bva = bi[n0a + nl], bvb = bi[n0b + nl];
#pragma unroll
        for (int r = 0; r < 4; r++) {
          hidden_s[(quad * 4 + r) * HP + n0a + nl] =
              __float2bfloat16(gelu_tanh(aca[r] + bva));
          hidden_s[(quad * 4 + r) * HP + n0b + nl] =
              __float2bfloat16(gelu_tanh(acb[r] + bvb));
        }
      }
    }
    __syncthreads();
    // ---- mix2: 28 n-tiles, 7/wave (3 pairs + 1); state update in LDS ----
    {
      bf16x8 ag[16];
#pragma unroll
      for (int j = 0; j < 16; j++)
        ag[j] = *(const bf16x8*)&hidden_s[nl * HP + j * 32 + quad * 8];

#define M2EPI(ACC, N0)                                                        \
      {                                                                       \
        int col = (N0) + nl;                                                  \
        if (col < DIMV) {                                                     \
          float bv = bo[col];                                                 \
          _Pragma("unroll")                                                   \
          for (int r = 0; r < 4; r++) {                                       \
            int qi = quad * 4 + r;                                            \
            if (qi < 8) {                                                     \
              float rr = ACC[r] + bv;                                         \
              if (col < 2) {                                                  \
                float v = pos_s[qi][col] + rr;                                \
                pos_s[qi][col] = v;                                           \
                if (it == 3) out[(q0 + qi) * 4 + col] = v;                    \
              } else if (col == 2) {                                          \
                float v = occ_s[qi] + rr; occ_s[qi] = v;                      \
                if (it == 3) out[(q0 + qi) * 4 + 2] = v;                      \
                mi_s[qi * MIP + 2] = __float2bfloat16(v);                     \
              } else if (col == 3) {                                          \
                float v = expd_s[qi] + rr; expd_s[qi] = v;                    \
                if (it == 3) out[(q0 + qi) * 4 + 3] = v;                      \
                mi_s[qi * MIP + 3] = __float2bfloat16(v);                     \
              } else {                                                        \
                float v = feats_s[qi][col - 4] + rr;                          \
                feats_s[qi][col - 4] = v;                                     \
                mi_s[qi * MIP + col] = __float2bfloat16(v);                   \
              }                                                               \
            }                                                                 \
          }                                                                   \
        }                                                                     \
      }

#pragma unroll
      for (int tp = 0; tp < 3; ++tp) {
        int n0a = (wv * 7 + tp * 2) * 16;
        int n0b = n0a + 16;
        const unsigned short* bpa = &WOT[(n0a + nl) * HID + quad * 8];
        const unsigned short* bpb = &WOT[(n0b + nl) * HID + quad * 8];
        f32x4 aca = {0.f, 0.f, 0.f, 0.f}, acb = {0.f, 0.f, 0.f, 0.f};
#pragma unroll
        for (int ks = 0; ks < 16; ks++) {
          bf16x8 ba = *(const bf16x8*)(bpa + ks * 32);
          bf16x8 bb = *(const bf16x8*)(bpb + ks * 32);
          aca = __builtin_amdgcn_mfma_f32_16x16x32_bf16(ag[ks], ba, aca, 0, 0, 0);
          acb = __builtin_amdgcn_mfma_f32_16x16x32_bf16(ag[ks], bb, acb, 0, 0, 0);
        }
        M2EPI(aca, n0a)
        M2EPI(acb, n0b)
      }
      {
        int n0 = (wv * 7 + 6) * 16;
        const unsigned short* bp = &WOT[(n0 + nl) * HID + quad * 8];
        f32x4 acc = {0.f, 0.f, 0.f, 0.f};
#pragma unroll
        for (int ks = 0; ks < 16; ks++) {
          bf16x8 b = *(const bf16x8*)(bp + ks * 32);
          acc = __builtin_amdgcn_mfma_f32_16x16x32_bf16(ag[ks], b, acc, 0, 0, 0);
        }
        M2EPI(acc, n0)
      }
#undef M2EPI
    }
    __syncthreads();
  }
}

// ---------------------------------------------------------------------------
extern "C" void kernel_launch(void* const* d_in, const int* in_sizes, int n_in,
                              void* d_out, int out_size, void* d_ws, size_t ws_size,
                              hipStream_t stream) {
  const float* fg = (const float*)d_in[0];
  const float* hg = (const float*)d_in[1];
  const float* qf = (const float*)d_in[2];
  const float* hq = (const float*)d_in[3];
  const float* w1 = (const float*)d_in[4];
  const float* b1 = (const float*)d_in[5];
  const float* w2 = (const float*)d_in[6];
  const float* b2 = (const float*)d_in[7];
  const float* w3 = (const float*)d_in[8];
  const float* b3 = (const float*)d_in[9];
  const float* w4 = (const float*)d_in[10];
  const float* b4 = (const float*)d_in[11];
  const float* w5 = (const float*)d_in[12];
  const float* b5 = (const float*)d_in[13];
  const float* wi = (const float*)d_in[14];
  const float* bi = (const float*)d_in[15];
  const float* wo = (const float*)d_in[16];
  const float* bo = (const float*)d_in[17];
  float* ws = (float*)d_ws;
  float* out = (float*)d_out;

  k_prep_cv<<<11742, 256, 0, stream>>>(fg, hg, qf, hq, w3, w2, wi, wo, ws);
  k_head_stripe<<<16384, 256, 0, stream>>>(w1, b1, b2, b3, ws);
  k_refine<<<128, 256, 0, stream>>>(w4, b4, w5, b5, bi, bo, ws, out);
}